// Round 12
// baseline (157.546 us; speedup 1.0000x reference)
//
#include <hip/hip_runtime.h>
#include <hip/hip_bf16.h>
#include <cmath>

// ---------------------------------------------------------------------------
// MultiSynonymsAttention: c=50 s=4 d=768 b=4 t=1024 z=12 h=64
// 4 dispatches:
//  prep     : WTk/q/v = bf16(W^T)                      (432 blocks)
//  gemm_qs  : QSbf = bf16(Q@WTq^T + bq) [208][768],
//             WQLbf = bf16(ql@WTv^T + bv) [64][768]    (36 blocks, f32 A inline)
//  attn_mega: per (b,z,ts): K-tile GEMM (H f32 staged inline, z-slice captured
//             to THl) -> tanh -> K in LDS; tanh(THl); kw tile (MFMA, LDS);
//             scores (MFMA) + exp-sums (no max: |score| <~ 15) -> pd/pn
//  reduce   : block per (b,c), 64 lanes; ratio per (z,s), wave-reduce
// R11 fix: ws layout units — each WT is 589,824 bf16 = 294,912 f32 SLOTS;
// round-8 spacing (147,456 f32) made WTq/WTv overlap WTk (z>=6 clobbered).
// ---------------------------------------------------------------------------

typedef __attribute__((ext_vector_type(8))) short bf8_t;
typedef __attribute__((ext_vector_type(4))) float f32x4;

__device__ inline unsigned short f2bf(float x) {            // RNE f32->bf16
    unsigned u = __float_as_uint(x);
    return (unsigned short)((u + 0x7fffu + ((u >> 16) & 1u)) >> 16);
}
__device__ inline float bf2f(unsigned short u) {
    return __uint_as_float(((unsigned)u) << 16);
}
__device__ inline float ftanh(float x) {                    // 1 - 2/(e^2x+1)
    float t = __expf(2.f * x);                              // +inf -> 1
    return 1.f - 2.f * __builtin_amdgcn_rcpf(t + 1.f);      // -inf -> -1
}

// ---- prep: W^T -> bf16 for the 3 weight matrices --------------------------
__global__ __launch_bounds__(256) void prep_kernel(
    const float* __restrict__ WK, const float* __restrict__ WQ,
    const float* __restrict__ WV,
    unsigned short* __restrict__ WTk, unsigned short* __restrict__ WTq,
    unsigned short* __restrict__ WTv)
{
    __shared__ unsigned short tile[64][72];
    const int bid = blockIdx.x, tid = threadIdx.x;
    const int wsel = bid / 144, l = bid % 144;
    const float* W = (wsel == 0) ? WK : (wsel == 1) ? WQ : WV;
    unsigned short* WT = (wsel == 0) ? WTk : (wsel == 1) ? WTq : WTv;
    const int bn = (l % 12) * 64, bk = (l / 12) * 64;
    const int k = tid >> 4, n4 = (tid & 15) << 2;
#pragma unroll
    for (int i = 0; i < 4; i++) {
        int kk = k + i * 16;
        float4 v = *(const float4*)&W[(size_t)(bk + kk) * 768 + bn + n4];
        tile[n4 + 0][kk] = f2bf(v.x);
        tile[n4 + 1][kk] = f2bf(v.y);
        tile[n4 + 2][kk] = f2bf(v.z);
        tile[n4 + 3][kk] = f2bf(v.w);
    }
    __syncthreads();
#pragma unroll
    for (int i = 0; i < 2; i++) {
        int idx = tid + i * 256;
        int n = idx >> 3, k8 = (idx & 7) << 3;
        *(bf8_t*)&WT[(size_t)(bn + n) * 768 + bk + k8] = *(const bf8_t*)&tile[n][k8];
    }
}

// ---- small bf16 MFMA GEMM for QS / WQL; A staged from f32 inline ----------
// bid [0,24): QS (M=200, out 208 rows); [24,36): WQL (M=50, out 64 rows)
__global__ __launch_bounds__(256) void gemm_qs_kernel(
    const float* __restrict__ Q, const float* __restrict__ ql,
    const unsigned short* __restrict__ WTq, const unsigned short* __restrict__ WTv,
    const float* __restrict__ bq, const float* __restrict__ bv,
    unsigned short* __restrict__ QSbf, unsigned short* __restrict__ WQLbf)
{
    __shared__ unsigned short Al[128][72];
    __shared__ unsigned short Bl[64][72];
    const int bid = blockIdx.x, tid = threadIdx.x;
    int bm, bn, Mr, Mw;
    const float* A;
    const unsigned short* B;
    const float* bias;
    unsigned short* outp;
    if (bid < 24) {
        bm = (bid / 12) * 128; bn = (bid % 12) * 64;
        A = Q; B = WTq; bias = bq; Mr = 200; Mw = 208; outp = QSbf;
    } else {
        bm = 0; bn = (bid - 24) * 64;
        A = ql; B = WTv; bias = bv; Mr = 50; Mw = 64; outp = WQLbf;
    }
    const int lane = tid & 63, w = tid >> 6;
    const int wm = (w & 1) * 64, wn = (w >> 1) * 32;
    const int fr = lane & 15, fg = lane >> 4;

    f32x4 acc[4][2] = {};
    for (int k0 = 0; k0 < 768; k0 += 64) {
#pragma unroll
        for (int i = 0; i < 4; i++) {
            int f = tid + i * 256;
            int r = f >> 3, c8 = (f & 7) << 3;
            unsigned short t8[8] = {0, 0, 0, 0, 0, 0, 0, 0};
            if (bm + r < Mr) {
                float4 v0 = *(const float4*)&A[(size_t)(bm + r) * 768 + k0 + c8];
                float4 v1 = *(const float4*)&A[(size_t)(bm + r) * 768 + k0 + c8 + 4];
                t8[0] = f2bf(v0.x); t8[1] = f2bf(v0.y); t8[2] = f2bf(v0.z); t8[3] = f2bf(v0.w);
                t8[4] = f2bf(v1.x); t8[5] = f2bf(v1.y); t8[6] = f2bf(v1.z); t8[7] = f2bf(v1.w);
            }
            *(bf8_t*)&Al[r][c8] = *(const bf8_t*)t8;
        }
#pragma unroll
        for (int i = 0; i < 2; i++) {
            int f = tid + i * 256;
            int r = f >> 3, c8 = (f & 7) << 3;
            *(bf8_t*)&Bl[r][c8] = *(const bf8_t*)&B[(size_t)(bn + r) * 768 + k0 + c8];
        }
        __syncthreads();
#pragma unroll
        for (int kk = 0; kk < 2; kk++) {
            bf8_t a[4], bb[2];
#pragma unroll
            for (int mt = 0; mt < 4; mt++)
                a[mt] = *(const bf8_t*)&Al[wm + mt * 16 + fr][kk * 32 + fg * 8];
#pragma unroll
            for (int nt = 0; nt < 2; nt++)
                bb[nt] = *(const bf8_t*)&Bl[wn + nt * 16 + fr][kk * 32 + fg * 8];
#pragma unroll
            for (int mt = 0; mt < 4; mt++)
#pragma unroll
                for (int nt = 0; nt < 2; nt++)
                    acc[mt][nt] = __builtin_amdgcn_mfma_f32_16x16x32_bf16(
                        a[mt], bb[nt], acc[mt][nt], 0, 0, 0);
        }
        __syncthreads();
    }
#pragma unroll
    for (int nt = 0; nt < 2; nt++) {
        int ng = bn + wn + nt * 16 + fr;
        float bvv = bias[ng];
#pragma unroll
        for (int mt = 0; mt < 4; mt++)
#pragma unroll
            for (int r = 0; r < 4; r++) {
                int rg = bm + wm + mt * 16 + fg * 4 + r;
                if (rg < Mw)
                    outp[(size_t)rg * 768 + ng] = f2bf(acc[mt][nt][r] + bvv);
            }
    }
}

// ---- attn_mega: fused K-GEMM + tanh + kw + scores + exp-sums --------------
// block = (b, z, ts); XCD-swizzled so the 12 z-blocks of one (b,ts) share L2.
__global__ __launch_bounds__(256) void attn_mega_kernel(
    const float* __restrict__ H, const unsigned short* __restrict__ WTk,
    const float* __restrict__ bk,
    const unsigned short* __restrict__ QSbf, const unsigned short* __restrict__ WQLbf,
    float* __restrict__ pd, float* __restrict__ pn)
{
    // LDS pool: Al(K-tile) | THl | Bl.  kwl aliases [THl..Bl] after last read.
    __shared__ __align__(16) unsigned short pool[23040];   // 46,080 B
    unsigned short (*Al)[72]  = (unsigned short (*)[72])(pool);
    unsigned short (*THl)[72] = (unsigned short (*)[72])(pool + 9216);
    unsigned short (*Bl)[72]  = (unsigned short (*)[72])(pool + 18432);
    float (*kwl)[50]          = (float (*)[50])(pool + 9216);  // 25.6 KB <= 27.6

    int bid = blockIdx.x;
    bid = (bid & 7) * 48 + (bid >> 3);         // bijective: 384 = 8 * 48
    const int z = bid % 12;
    const int g = bid / 12;
    const int b = g >> 3, ts = g & 7;
    const int tid = threadIdx.x;
    const int lane = tid & 63, w = tid >> 6;
    const int wm = (w & 1) * 64, wn = (w >> 1) * 32;
    const int fr = lane & 15, fg = lane >> 4;
    const size_t hrow = (size_t)(b * 1024 + ts * 128);

    // ---- phase A: K-tile GEMM over K=768; capture H z-slice into THl ----
    f32x4 acc[4][2] = {};
    for (int k0 = 0; k0 < 768; k0 += 64) {
        const bool cap = (k0 == z * 64);
#pragma unroll
        for (int i = 0; i < 4; i++) {
            int f = tid + i * 256;
            int r = f >> 3, c8 = (f & 7) << 3;
            float4 v0 = *(const float4*)&H[(hrow + r) * 768 + k0 + c8];
            float4 v1 = *(const float4*)&H[(hrow + r) * 768 + k0 + c8 + 4];
            unsigned short t8[8] = {f2bf(v0.x), f2bf(v0.y), f2bf(v0.z), f2bf(v0.w),
                                    f2bf(v1.x), f2bf(v1.y), f2bf(v1.z), f2bf(v1.w)};
            *(bf8_t*)&Al[r][c8] = *(const bf8_t*)t8;
            if (cap) *(bf8_t*)&THl[r][c8] = *(const bf8_t*)t8;
        }
#pragma unroll
        for (int i = 0; i < 2; i++) {
            int f = tid + i * 256;
            int r = f >> 3, c8 = (f & 7) << 3;
            *(bf8_t*)&Bl[r][c8] = *(const bf8_t*)&WTk[(size_t)(z * 64 + r) * 768 + k0 + c8];
        }
        __syncthreads();
#pragma unroll
        for (int kk = 0; kk < 2; kk++) {
            bf8_t a[4], bb[2];
#pragma unroll
            for (int mt = 0; mt < 4; mt++)
                a[mt] = *(const bf8_t*)&Al[wm + mt * 16 + fr][kk * 32 + fg * 8];
#pragma unroll
            for (int nt = 0; nt < 2; nt++)
                bb[nt] = *(const bf8_t*)&Bl[wn + nt * 16 + fr][kk * 32 + fg * 8];
#pragma unroll
            for (int mt = 0; mt < 4; mt++)
#pragma unroll
                for (int nt = 0; nt < 2; nt++)
                    acc[mt][nt] = __builtin_amdgcn_mfma_f32_16x16x32_bf16(
                        a[mt], bb[nt], acc[mt][nt], 0, 0, 0);
        }
        __syncthreads();
    }

    // ---- phase B (no barrier needed until end): ----
    // B1: epilogue K-tile -> Al (bf16, tanh). C/D: col=lane&15, row=(lane>>4)*4+reg
#pragma unroll
    for (int nt = 0; nt < 2; nt++) {
        int hh = wn + nt * 16 + fr;
        float bvv = bk[z * 64 + hh];
#pragma unroll
        for (int mt = 0; mt < 4; mt++)
#pragma unroll
            for (int r = 0; r < 4; r++)
                Al[wm + mt * 16 + fg * 4 + r][hh] = f2bf(ftanh(acc[mt][nt][r] + bvv));
    }
    // B2: tanh THl in place
#pragma unroll
    for (int i = 0; i < 4; i++) {
        int f = tid + i * 256;
        int r = f >> 3, c8 = (f & 7) << 3;
        bf8_t v = *(const bf8_t*)&THl[r][c8];
        unsigned short t8[8];
#pragma unroll
        for (int j = 0; j < 8; j++)
            t8[j] = f2bf(ftanh(bf2f((unsigned short)v[j])));
        *(bf8_t*)&THl[r][c8] = *(const bf8_t*)t8;
    }
    // B3: stage WQL slice into Bl
#pragma unroll
    for (int i = 0; i < 2; i++) {
        int f = tid + i * 256;
        int r = f >> 3, c8 = (f & 7) << 3;
        *(bf8_t*)&Bl[r][c8] = *(const bf8_t*)&WQLbf[(size_t)r * 768 + z * 64 + c8];
    }
    __syncthreads();

    // ---- phase C: kw tile = tanh(H) @ WQL^T  (M=32/wave x N=64, K=64) ----
    {
        const int wm2 = w * 32;
        f32x4 a1[2][4] = {};
#pragma unroll
        for (int kk = 0; kk < 2; kk++) {
            bf8_t a[2], bb[4];
#pragma unroll
            for (int mt = 0; mt < 2; mt++)
                a[mt] = *(const bf8_t*)&THl[wm2 + mt * 16 + fr][kk * 32 + fg * 8];
#pragma unroll
            for (int nt = 0; nt < 4; nt++)
                bb[nt] = *(const bf8_t*)&Bl[nt * 16 + fr][kk * 32 + fg * 8];
#pragma unroll
            for (int mt = 0; mt < 2; mt++)
#pragma unroll
                for (int nt = 0; nt < 4; nt++)
                    a1[mt][nt] = __builtin_amdgcn_mfma_f32_16x16x32_bf16(
                        a[mt], bb[nt], a1[mt][nt], 0, 0, 0);
        }
        __syncthreads();   // all THl/Bl reads done; kwl may overwrite
#pragma unroll
        for (int nt = 0; nt < 4; nt++) {
            int c = nt * 16 + fr;
            if (c < 50) {
#pragma unroll
                for (int mt = 0; mt < 2; mt++)
#pragma unroll
                    for (int r = 0; r < 4; r++)
                        kwl[wm2 + mt * 16 + fg * 4 + r][c] = a1[mt][nt][r];
            }
        }
    }
    __syncthreads();

    // ---- phase D: scores + exp-sums. wave w owns cs-tiles nt=w,w+4,w+8[,12]
    bf8_t af[16];
#pragma unroll
    for (int mt = 0; mt < 8; mt++)
#pragma unroll
        for (int kk = 0; kk < 2; kk++)
            af[mt * 2 + kk] = *(const bf8_t*)&Al[mt * 16 + fr][kk * 32 + fg * 8];

    for (int nt = w; nt < 13; nt += 4) {
        const int cs = nt * 16 + fr;
        const bool live = (cs < 200);
        const int kc = live ? (cs >> 2) : 0;
        bf8_t b0 = *(const bf8_t*)&QSbf[(size_t)(nt * 16 + fr) * 768 + z * 64 + fg * 8];
        bf8_t b1 = *(const bf8_t*)&QSbf[(size_t)(nt * 16 + fr) * 768 + z * 64 + 32 + fg * 8];

        float den = 0.f, num = 0.f;
#pragma unroll
        for (int mt = 0; mt < 8; mt++) {
            f32x4 sc = {};
            sc = __builtin_amdgcn_mfma_f32_16x16x32_bf16(af[mt * 2 + 0], b0, sc, 0, 0, 0);
            sc = __builtin_amdgcn_mfma_f32_16x16x32_bf16(af[mt * 2 + 1], b1, sc, 0, 0, 0);
#pragma unroll
            for (int j = 0; j < 4; j++) {
                float p = __expf(sc[j]);               // |score| <~ 15: f32-safe
                den += p;
                num += p * kwl[mt * 16 + fg * 4 + j][kc];
            }
        }
        den += __shfl_xor(den, 16); num += __shfl_xor(num, 16);
        den += __shfl_xor(den, 32); num += __shfl_xor(num, 32);
        if (fg == 0 && live) {
            size_t R = ((size_t)b * 200 + cs) * 12 + z;
            pd[R * 8 + ts] = den;
            pn[R * 8 + ts] = num;
        }
    }
}

// ---- reduce: block per (b,c); lane j<48 owns (z,s); wave-reduce ratios ----
__global__ __launch_bounds__(64) void reduce_kernel(
    const float* __restrict__ pd, const float* __restrict__ pn,
    float* __restrict__ out)
{
    const int bc = blockIdx.x;           // b*50 + c
    const int b = bc / 50, c = bc % 50;
    const int j = threadIdx.x;
    float ratio = 0.f;
    if (j < 48) {
        int zz = j >> 2, s = j & 3;
        size_t R = ((size_t)b * 200 + (c * 4 + s)) * 12 + zz;
        float D = 0.f, N = 0.f;
#pragma unroll
        for (int t = 0; t < 8; t++) {
            D += pd[R * 8 + t];
            N += pn[R * 8 + t];
        }
        ratio = N / D;
    }
#pragma unroll
    for (int off = 32; off; off >>= 1) ratio += __shfl_xor(ratio, off);
    if (j == 0) out[bc] = 0.25f * ratio;
}

extern "C" void kernel_launch(void* const* d_in, const int* in_sizes, int n_in,
                              void* d_out, int out_size, void* d_ws, size_t ws_size,
                              hipStream_t stream) {
    const float* Q    = (const float*)d_in[0];
    const float* H    = (const float*)d_in[1];
    const float* ql   = (const float*)d_in[2];
    const float* WQ_w = (const float*)d_in[3];
    const float* WQ_b = (const float*)d_in[4];
    const float* WK_w = (const float*)d_in[5];
    const float* WK_b = (const float*)d_in[6];
    const float* WV_w = (const float*)d_in[7];
    const float* WV_b = (const float*)d_in[8];
    float* out = (float*)d_out;

    // ws layout in f32 SLOTS. Each WT = 768*768 bf16 = 589,824 us = 294,912 f32.
    float* ws = (float*)d_ws;
    unsigned short* WTk   = (unsigned short*)ws;              // [0,      294912)
    unsigned short* WTq   = (unsigned short*)(ws + 294912);   // [294912, 589824)
    unsigned short* WTv   = (unsigned short*)(ws + 589824);   // [589824, 884736)
    unsigned short* QSbf  = (unsigned short*)(ws + 884736);   // 208*768 us = 79,872 f32
    unsigned short* WQLbf = (unsigned short*)(ws + 964608);   //  64*768 us = 24,576 f32
    float* pd             = ws + 989184;                      //  76,800 f32
    float* pn             = ws + 1065984;                     //  76,800 f32
    (void)in_sizes; (void)n_in; (void)out_size; (void)ws_size;

    prep_kernel<<<432, 256, 0, stream>>>(WK_w, WQ_w, WV_w, WTk, WTq, WTv);
    gemm_qs_kernel<<<36, 256, 0, stream>>>(Q, ql, WTq, WTv, WQ_b, WV_b, QSbf, WQLbf);
    attn_mega_kernel<<<384, 256, 0, stream>>>(H, WTk, WK_b, QSbf, WQLbf, pd, pn);
    reduce_kernel<<<200, 64, 0, stream>>>(pd, pn, out);
}

// Round 13
// 121.265 us; speedup vs baseline: 1.2992x; 1.2992x over previous
//
#include <hip/hip_runtime.h>
#include <hip/hip_bf16.h>
#include <cmath>

// ---------------------------------------------------------------------------
// MultiSynonymsAttention: c=50 s=4 d=768 b=4 t=1024 z=12 h=64
// 4 dispatches (round-8 split pipeline, re-parallelized with 64-row tiles):
//  prep    : Hbf=bf16(H) (1536 blks), WTk/q/v=bf16(W^T) (432 blks)
//  gemm_all: job0 KSb = bf16(ftanh(Hbf@WTk^T + bk)) [b][z][t][64], 768 blks
//            (64-row tiles, XCD-swizzled); job1 QSbf [208][768] (48 blks,
//            f32 A inline); job2 WQLbf [64][768] (12 blks)
//  attn7   : block=(b,z,ts16): tanh(Hbf) 64x64 -> kwl (MFMA) ; K tile ;
//            scores (MFMA) + exp-sums (no max: |score|<~15) -> pd/pn x16
//  reduce  : block per (b,c); lane j<48 owns (z,s); sums 16 t-partials
// ---------------------------------------------------------------------------

typedef __attribute__((ext_vector_type(8))) short bf8_t;
typedef __attribute__((ext_vector_type(4))) float f32x4;

__device__ inline unsigned short f2bf(float x) {            // RNE f32->bf16
    unsigned u = __float_as_uint(x);
    return (unsigned short)((u + 0x7fffu + ((u >> 16) & 1u)) >> 16);
}
__device__ inline float bf2f(unsigned short u) {
    return __uint_as_float(((unsigned)u) << 16);
}
__device__ inline float ftanh(float x) {                    // 1 - 2/(e^2x+1)
    float t = __expf(2.f * x);                              // +inf -> 1
    return 1.f - 2.f * __builtin_amdgcn_rcpf(t + 1.f);      // -inf -> -1
}

// ---- prep: Hbf + 3x W^T in one launch -------------------------------------
// [0,1536): H -> Hbf ; [1536,1968): W^T -> bf16
__global__ __launch_bounds__(256) void prep_kernel(
    const float* __restrict__ H, const float* __restrict__ WK,
    const float* __restrict__ WQ, const float* __restrict__ WV,
    unsigned short* __restrict__ Hbf,
    unsigned short* __restrict__ WTk, unsigned short* __restrict__ WTq,
    unsigned short* __restrict__ WTv)
{
    __shared__ unsigned short tile[64][72];
    const int bid = blockIdx.x, tid = threadIdx.x;
    if (bid < 1536) {
        int i = (bid * 256 + tid) * 8;
        float4 v0 = *(const float4*)&H[i];
        float4 v1 = *(const float4*)&H[i + 4];
        unsigned short h8[8] = {f2bf(v0.x), f2bf(v0.y), f2bf(v0.z), f2bf(v0.w),
                                f2bf(v1.x), f2bf(v1.y), f2bf(v1.z), f2bf(v1.w)};
        *(bf8_t*)&Hbf[i] = *(const bf8_t*)h8;
    } else {
        int j = bid - 1536;
        int wsel = j / 144, l = j % 144;
        const float* W = (wsel == 0) ? WK : (wsel == 1) ? WQ : WV;
        unsigned short* WT = (wsel == 0) ? WTk : (wsel == 1) ? WTq : WTv;
        const int bn = (l % 12) * 64, bk = (l / 12) * 64;
        const int k = tid >> 4, n4 = (tid & 15) << 2;
#pragma unroll
        for (int i = 0; i < 4; i++) {
            int kk = k + i * 16;
            float4 v = *(const float4*)&W[(size_t)(bk + kk) * 768 + bn + n4];
            tile[n4 + 0][kk] = f2bf(v.x);
            tile[n4 + 1][kk] = f2bf(v.y);
            tile[n4 + 2][kk] = f2bf(v.z);
            tile[n4 + 3][kk] = f2bf(v.w);
        }
        __syncthreads();
#pragma unroll
        for (int i = 0; i < 2; i++) {
            int idx = tid + i * 256;
            int n = idx >> 3, k8 = (idx & 7) << 3;
            *(bf8_t*)&WT[(size_t)(bn + n) * 768 + bk + k8] = *(const bf8_t*)&tile[n][k8];
        }
    }
}

// ---- unified bf16 MFMA GEMM: 64x64 tiles, K=768, 3 job types --------------
// bid [0,768): job0 KS (XCD-swizzled; z=bid%12, bm=(bid/12)*64)
// [768,816): job1 QS (f32 A inline) ; [816,828): job2 WQL
__global__ __launch_bounds__(256) void gemm_all_kernel(
    const unsigned short* __restrict__ Hbf,
    const float* __restrict__ Q, const float* __restrict__ ql,
    const unsigned short* __restrict__ WTk, const unsigned short* __restrict__ WTq,
    const unsigned short* __restrict__ WTv,
    const float* __restrict__ bk, const float* __restrict__ bq,
    const float* __restrict__ bv,
    unsigned short* __restrict__ KSb, unsigned short* __restrict__ QSbf,
    unsigned short* __restrict__ WQLbf)
{
    __shared__ unsigned short Al[64][72];
    __shared__ unsigned short Bl[64][72];
    int bid = blockIdx.x;
    const int tid = threadIdx.x;
    // XCD-swizzle job0 (768 = 8*96, bijective): 12 z-variants of one Hbf
    // A-tile are orig-consecutive -> same XCD L2.
    if (bid < 768) bid = (bid & 7) * 96 + (bid >> 3);
    int job, bm, bn, Mr = 0, Mw = 0, z = 0;
    const float* Af = nullptr;
    const unsigned short* B;
    const float* bias;
    if (bid < 768) {
        job = 0; z = bid % 12; bm = (bid / 12) * 64; bn = z * 64;
        B = WTk; bias = bk;
    } else if (bid < 816) {
        int l = bid - 768;
        job = 1; bm = (l / 12) * 64; bn = (l % 12) * 64;
        Af = Q; B = WTq; bias = bq; Mr = 200; Mw = 208;
    } else {
        job = 2; bm = 0; bn = (bid - 816) * 64;
        Af = ql; B = WTv; bias = bv; Mr = 50; Mw = 64;
    }
    const int lane = tid & 63, w = tid >> 6;
    const int wm = (w & 1) * 32, wn = (w >> 1) * 32;
    const int fr = lane & 15, fg = lane >> 4;

    f32x4 acc[2][2] = {};
    for (int k0 = 0; k0 < 768; k0 += 64) {
#pragma unroll
        for (int i = 0; i < 2; i++) {
            int f = tid + i * 256;
            int r = f >> 3, c8 = (f & 7) << 3;
            if (job == 0) {
                *(bf8_t*)&Al[r][c8] =
                    *(const bf8_t*)&Hbf[(size_t)(bm + r) * 768 + k0 + c8];
            } else {
                unsigned short t8[8] = {0, 0, 0, 0, 0, 0, 0, 0};
                if (bm + r < Mr) {
                    float4 v0 = *(const float4*)&Af[(size_t)(bm + r) * 768 + k0 + c8];
                    float4 v1 = *(const float4*)&Af[(size_t)(bm + r) * 768 + k0 + c8 + 4];
                    t8[0] = f2bf(v0.x); t8[1] = f2bf(v0.y);
                    t8[2] = f2bf(v0.z); t8[3] = f2bf(v0.w);
                    t8[4] = f2bf(v1.x); t8[5] = f2bf(v1.y);
                    t8[6] = f2bf(v1.z); t8[7] = f2bf(v1.w);
                }
                *(bf8_t*)&Al[r][c8] = *(const bf8_t*)t8;
            }
        }
#pragma unroll
        for (int i = 0; i < 2; i++) {
            int f = tid + i * 256;
            int r = f >> 3, c8 = (f & 7) << 3;
            *(bf8_t*)&Bl[r][c8] = *(const bf8_t*)&B[(size_t)(bn + r) * 768 + k0 + c8];
        }
        __syncthreads();
#pragma unroll
        for (int kk = 0; kk < 2; kk++) {
            bf8_t a[2], bb[2];
#pragma unroll
            for (int mt = 0; mt < 2; mt++)
                a[mt] = *(const bf8_t*)&Al[wm + mt * 16 + fr][kk * 32 + fg * 8];
#pragma unroll
            for (int nt = 0; nt < 2; nt++)
                bb[nt] = *(const bf8_t*)&Bl[wn + nt * 16 + fr][kk * 32 + fg * 8];
#pragma unroll
            for (int mt = 0; mt < 2; mt++)
#pragma unroll
                for (int nt = 0; nt < 2; nt++)
                    acc[mt][nt] = __builtin_amdgcn_mfma_f32_16x16x32_bf16(
                        a[mt], bb[nt], acc[mt][nt], 0, 0, 0);
        }
        __syncthreads();
    }
    // C/D: col = lane&15, row = (lane>>4)*4 + reg   [m89/m91]
#pragma unroll
    for (int nt = 0; nt < 2; nt++) {
        int ng = bn + wn + nt * 16 + fr;
        float bvv = bias[ng];
        if (job == 0) {
            int hh = ng & 63;
#pragma unroll
            for (int mt = 0; mt < 2; mt++) {
#pragma unroll
                for (int r = 0; r < 4; r++) {
                    int rg = bm + wm + mt * 16 + fg * 4 + r;
                    int bb2 = rg >> 10, t = rg & 1023;
                    KSb[(((size_t)bb2 * 12 + z) * 1024 + t) * 64 + hh] =
                        f2bf(ftanh(acc[mt][nt][r] + bvv));
                }
            }
        } else {
            unsigned short* outp = (job == 1) ? QSbf : WQLbf;
#pragma unroll
            for (int mt = 0; mt < 2; mt++) {
#pragma unroll
                for (int r = 0; r < 4; r++) {
                    int rg = bm + wm + mt * 16 + fg * 4 + r;
                    if (rg < Mw)
                        outp[(size_t)rg * 768 + ng] = f2bf(acc[mt][nt][r] + bvv);
                }
            }
        }
    }
}

// ---- attn7: 64-row t-chunks; kwl (MFMA) + scores (MFMA) + exp-sums --------
// block = (b, z, ts of 64 t); 768 blocks; 4 waves.
__global__ __launch_bounds__(256) void attn7_kernel(
    const unsigned short* __restrict__ KSb, const unsigned short* __restrict__ QSbf,
    const unsigned short* __restrict__ Hbf, const unsigned short* __restrict__ WQLbf,
    float* __restrict__ pd, float* __restrict__ pn)
{
    __shared__ unsigned short KTl[64][72];   // phase1: tanh(H); phase3: K tile
    __shared__ unsigned short Wl[64][72];
    __shared__ float kwl[64][50];
    const int blk = blockIdx.x;
    const int ts = blk & 15;
    const int z  = (blk >> 4) % 12;
    const int b  = blk / 192;
    const int tid = threadIdx.x;
    const int lane = tid & 63, w = tid >> 6;
    const int fr = lane & 15, fg = lane >> 4;

    // phase 0: stage tanh(Hbf z-slice) rows ts*64..+64 + WQL slice
    const unsigned short* hb = Hbf + (size_t)(b * 1024 + ts * 64) * 768 + z * 64;
#pragma unroll
    for (int i = 0; i < 2; i++) {
        int f = tid + i * 256;
        int r = f >> 3, c8 = (f & 7) << 3;
        bf8_t v = *(const bf8_t*)&hb[(size_t)r * 768 + c8];
        unsigned short t8[8];
#pragma unroll
        for (int j = 0; j < 8; j++)
            t8[j] = f2bf(ftanh(bf2f((unsigned short)v[j])));
        *(bf8_t*)&KTl[r][c8] = *(const bf8_t*)t8;
    }
#pragma unroll
    for (int i = 0; i < 2; i++) {
        int f = tid + i * 256;
        int r = f >> 3, c8 = (f & 7) << 3;
        *(bf8_t*)&Wl[r][c8] = *(const bf8_t*)&WQLbf[(size_t)r * 768 + z * 64 + c8];
    }
    __syncthreads();

    // phase 1: kwl = tanh(H) @ WQL^T (wave w: rows w*16..+16; N=64, K=64)
    {
        const int wm2 = w * 16;
        f32x4 a1[4] = {};
#pragma unroll
        for (int kk = 0; kk < 2; kk++) {
            bf8_t a = *(const bf8_t*)&KTl[wm2 + fr][kk * 32 + fg * 8];
#pragma unroll
            for (int nt = 0; nt < 4; nt++) {
                bf8_t bb = *(const bf8_t*)&Wl[nt * 16 + fr][kk * 32 + fg * 8];
                a1[nt] = __builtin_amdgcn_mfma_f32_16x16x32_bf16(a, bb, a1[nt], 0, 0, 0);
            }
        }
#pragma unroll
        for (int nt = 0; nt < 4; nt++) {
            int c = nt * 16 + fr;
            if (c < 50) {
#pragma unroll
                for (int r = 0; r < 4; r++)
                    kwl[wm2 + fg * 4 + r][c] = a1[nt][r];
            }
        }
    }
    __syncthreads();

    // phase 2: stage K tile over the tanh(H) tile
    const unsigned short* ksb = KSb + ((size_t)((b * 12 + z) * 1024) + ts * 64) * 64;
#pragma unroll
    for (int i = 0; i < 2; i++) {
        int f = tid + i * 256;
        int r = f >> 3, c8 = (f & 7) << 3;
        *(bf8_t*)&KTl[r][c8] = *(const bf8_t*)&ksb[(size_t)r * 64 + c8];
    }
    __syncthreads();

    // phase 3: scores + exp-sums. wave w owns cs-tiles nt = w, w+4, w+8[, 12].
    bf8_t af[8];
#pragma unroll
    for (int mt = 0; mt < 4; mt++)
#pragma unroll
        for (int kk = 0; kk < 2; kk++)
            af[mt * 2 + kk] = *(const bf8_t*)&KTl[mt * 16 + fr][kk * 32 + fg * 8];

    for (int nt = w; nt < 13; nt += 4) {
        const int cs = nt * 16 + fr;
        const bool live = (cs < 200);
        const int kc = live ? (cs >> 2) : 0;
        bf8_t b0 = *(const bf8_t*)&QSbf[(size_t)(nt * 16 + fr) * 768 + z * 64 + fg * 8];
        bf8_t b1 = *(const bf8_t*)&QSbf[(size_t)(nt * 16 + fr) * 768 + z * 64 + 32 + fg * 8];

        float den = 0.f, num = 0.f;
#pragma unroll
        for (int mt = 0; mt < 4; mt++) {
            f32x4 sc = {};
            sc = __builtin_amdgcn_mfma_f32_16x16x32_bf16(af[mt * 2 + 0], b0, sc, 0, 0, 0);
            sc = __builtin_amdgcn_mfma_f32_16x16x32_bf16(af[mt * 2 + 1], b1, sc, 0, 0, 0);
#pragma unroll
            for (int j = 0; j < 4; j++) {
                float p = __expf(sc[j]);               // |score| <~ 15: f32-safe
                den += p;
                num += p * kwl[mt * 16 + fg * 4 + j][kc];
            }
        }
        den += __shfl_xor(den, 16); num += __shfl_xor(num, 16);
        den += __shfl_xor(den, 32); num += __shfl_xor(num, 32);
        if (fg == 0 && live) {
            size_t R = ((size_t)b * 200 + cs) * 12 + z;
            pd[R * 16 + ts] = den;
            pn[R * 16 + ts] = num;
        }
    }
}

// ---- reduce: block per (b,c); lane j<48 owns (z,s); 16 t-partials ---------
__global__ __launch_bounds__(64) void reduce_kernel(
    const float* __restrict__ pd, const float* __restrict__ pn,
    float* __restrict__ out)
{
    const int bc = blockIdx.x;           // b*50 + c
    const int b = bc / 50, c = bc % 50;
    const int j = threadIdx.x;
    float ratio = 0.f;
    if (j < 48) {
        int zz = j >> 2, s = j & 3;
        size_t R = ((size_t)b * 200 + (c * 4 + s)) * 12 + zz;
        float D = 0.f, N = 0.f;
#pragma unroll
        for (int t = 0; t < 16; t++) {
            D += pd[R * 16 + t];
            N += pn[R * 16 + t];
        }
        ratio = N / D;
    }
#pragma unroll
    for (int off = 32; off; off >>= 1) ratio += __shfl_xor(ratio, off);
    if (j == 0) out[bc] = 0.25f * ratio;
}

extern "C" void kernel_launch(void* const* d_in, const int* in_sizes, int n_in,
                              void* d_out, int out_size, void* d_ws, size_t ws_size,
                              hipStream_t stream) {
    const float* Q    = (const float*)d_in[0];
    const float* H    = (const float*)d_in[1];
    const float* ql   = (const float*)d_in[2];
    const float* WQ_w = (const float*)d_in[3];
    const float* WQ_b = (const float*)d_in[4];
    const float* WK_w = (const float*)d_in[5];
    const float* WK_b = (const float*)d_in[6];
    const float* WV_w = (const float*)d_in[7];
    const float* WV_b = (const float*)d_in[8];
    float* out = (float*)d_out;

    // ws layout in f32 SLOTS (bf16 buffers use elem_count/2 slots):
    //  WT: 768*768 bf16 = 294,912 f32 ; Hbf: 4096*768 bf16 = 1,572,864 f32
    //  KSb: 1,572,864 ; QSbf: 208*768/2 = 79,872 ; WQLbf: 24,576
    //  pd/pn: 9600*16 = 153,600 each
    float* ws = (float*)d_ws;
    unsigned short* WTk   = (unsigned short*)ws;               // [0, 294912)
    unsigned short* WTq   = (unsigned short*)(ws + 294912);    // [294912, 589824)
    unsigned short* WTv   = (unsigned short*)(ws + 589824);    // [589824, 884736)
    unsigned short* Hbf   = (unsigned short*)(ws + 884736);    // [884736, 2457600)
    unsigned short* KSb   = (unsigned short*)(ws + 2457600);   // [2457600, 4030464)
    unsigned short* QSbf  = (unsigned short*)(ws + 4030464);   // [4030464, 4110336)
    unsigned short* WQLbf = (unsigned short*)(ws + 4110336);   // [4110336, 4134912)
    float* pd             = ws + 4134912;                      // [4134912, 4288512)
    float* pn             = ws + 4288512;                      // [4288512, 4442112)
    (void)in_sizes; (void)n_in; (void)out_size; (void)ws_size;

    prep_kernel<<<1968, 256, 0, stream>>>(H, WK_w, WQ_w, WV_w, Hbf, WTk, WTq, WTv);
    gemm_all_kernel<<<828, 256, 0, stream>>>(Hbf, Q, ql, WTk, WTq, WTv,
                                             WK_b, WQ_b, WV_b, KSb, QSbf, WQLbf);
    attn7_kernel<<<768, 256, 0, stream>>>(KSb, QSbf, Hbf, WQLbf, pd, pn);
    reduce_kernel<<<200, 64, 0, stream>>>(pd, pn, out);
}

// Round 15
// 117.688 us; speedup vs baseline: 1.3387x; 1.0304x over previous
//
#include <hip/hip_runtime.h>
#include <hip/hip_bf16.h>
#include <cmath>

// ---------------------------------------------------------------------------
// MultiSynonymsAttention: c=50 s=4 d=768 b=4 t=1024 z=12 h=64
// 4 dispatches (round-13 structure, Hbf round-trip eliminated):
//  prep    : WTk/q/v = bf16(W^T)                       (432 blocks)
//  gemm_all: 64x64 tiles, all jobs stage f32 A inline:
//            job0 KSb = bf16(ftanh(H@WTk^T + bk)) [b][z][t][64] (768 blks,
//            XCD-swizzled); job1 QSbf [208][768] (48); job2 WQLbf [64][768] (12)
//  attn7   : block=(b,z,ts16): tanh(f32 H) 64x64 -> kwl (MFMA); K tile;
//            scores (MFMA) + exp-sums (no max: |score|<~15) -> pd/pn x16
//  reduce  : block per (b,c); lane j<48 owns (z,s); sums 16 t-partials
// ---------------------------------------------------------------------------

typedef __attribute__((ext_vector_type(8))) short bf8_t;
typedef __attribute__((ext_vector_type(4))) float f32x4;

__device__ inline unsigned short f2bf(float x) {            // RNE f32->bf16
    unsigned u = __float_as_uint(x);
    return (unsigned short)((u + 0x7fffu + ((u >> 16) & 1u)) >> 16);
}
__device__ inline float ftanh(float x) {                    // 1 - 2/(e^2x+1)
    float t = __expf(2.f * x);                              // +inf -> 1
    return 1.f - 2.f * __builtin_amdgcn_rcpf(t + 1.f);      // -inf -> -1
}

// ---- prep: 3x W^T -> bf16 -------------------------------------------------
__global__ __launch_bounds__(256) void prep_kernel(
    const float* __restrict__ WK, const float* __restrict__ WQ,
    const float* __restrict__ WV,
    unsigned short* __restrict__ WTk, unsigned short* __restrict__ WTq,
    unsigned short* __restrict__ WTv)
{
    __shared__ unsigned short tile[64][72];
    const int bid = blockIdx.x, tid = threadIdx.x;
    const int wsel = bid / 144, l = bid % 144;
    const float* W = (wsel == 0) ? WK : (wsel == 1) ? WQ : WV;
    unsigned short* WT = (wsel == 0) ? WTk : (wsel == 1) ? WTq : WTv;
    const int bn = (l % 12) * 64, bk = (l / 12) * 64;
    const int k = tid >> 4, n4 = (tid & 15) << 2;
#pragma unroll
    for (int i = 0; i < 4; i++) {
        int kk = k + i * 16;
        float4 v = *(const float4*)&W[(size_t)(bk + kk) * 768 + bn + n4];
        tile[n4 + 0][kk] = f2bf(v.x);
        tile[n4 + 1][kk] = f2bf(v.y);
        tile[n4 + 2][kk] = f2bf(v.z);
        tile[n4 + 3][kk] = f2bf(v.w);
    }
    __syncthreads();
#pragma unroll
    for (int i = 0; i < 2; i++) {
        int idx = tid + i * 256;
        int n = idx >> 3, k8 = (idx & 7) << 3;
        *(bf8_t*)&WT[(size_t)(bn + n) * 768 + bk + k8] = *(const bf8_t*)&tile[n][k8];
    }
}

// ---- unified bf16 MFMA GEMM: 64x64 tiles, K=768, f32 A staged inline ------
// bid [0,768): job0 KS (XCD-swizzled; z=bid%12, bm=(bid/12)*64)
// [768,816): job1 QS ; [816,828): job2 WQL
__global__ __launch_bounds__(256) void gemm_all_kernel(
    const float* __restrict__ H, const float* __restrict__ Q,
    const float* __restrict__ ql,
    const unsigned short* __restrict__ WTk, const unsigned short* __restrict__ WTq,
    const unsigned short* __restrict__ WTv,
    const float* __restrict__ bk, const float* __restrict__ bq,
    const float* __restrict__ bv,
    unsigned short* __restrict__ KSb, unsigned short* __restrict__ QSbf,
    unsigned short* __restrict__ WQLbf)
{
    __shared__ unsigned short Al[64][72];
    __shared__ unsigned short Bl[64][72];
    int bid = blockIdx.x;
    const int tid = threadIdx.x;
    // XCD-swizzle job0 (768 = 8*96, bijective): 12 z-variants of one H
    // A-tile are orig-consecutive -> same XCD L2.
    if (bid < 768) bid = (bid & 7) * 96 + (bid >> 3);
    int job, bm, bn, Mr, Mw = 0, z = 0;
    const float* Af;
    const unsigned short* B;
    const float* bias;
    if (bid < 768) {
        job = 0; z = bid % 12; bm = (bid / 12) * 64; bn = z * 64;
        Af = H; B = WTk; bias = bk; Mr = 4096;
    } else if (bid < 816) {
        int l = bid - 768;
        job = 1; bm = (l / 12) * 64; bn = (l % 12) * 64;
        Af = Q; B = WTq; bias = bq; Mr = 200; Mw = 208;
    } else {
        job = 2; bm = 0; bn = (bid - 816) * 64;
        Af = ql; B = WTv; bias = bv; Mr = 50; Mw = 64;
    }
    const int lane = tid & 63, w = tid >> 6;
    const int wm = (w & 1) * 32, wn = (w >> 1) * 32;
    const int fr = lane & 15, fg = lane >> 4;

    f32x4 acc[2][2] = {};
    for (int k0 = 0; k0 < 768; k0 += 64) {
#pragma unroll
        for (int i = 0; i < 2; i++) {
            int f = tid + i * 256;
            int r = f >> 3, c8 = (f & 7) << 3;
            unsigned short t8[8] = {0, 0, 0, 0, 0, 0, 0, 0};
            if (bm + r < Mr) {
                float4 v0 = *(const float4*)&Af[(size_t)(bm + r) * 768 + k0 + c8];
                float4 v1 = *(const float4*)&Af[(size_t)(bm + r) * 768 + k0 + c8 + 4];
                t8[0] = f2bf(v0.x); t8[1] = f2bf(v0.y);
                t8[2] = f2bf(v0.z); t8[3] = f2bf(v0.w);
                t8[4] = f2bf(v1.x); t8[5] = f2bf(v1.y);
                t8[6] = f2bf(v1.z); t8[7] = f2bf(v1.w);
            }
            *(bf8_t*)&Al[r][c8] = *(const bf8_t*)t8;
        }
#pragma unroll
        for (int i = 0; i < 2; i++) {
            int f = tid + i * 256;
            int r = f >> 3, c8 = (f & 7) << 3;
            *(bf8_t*)&Bl[r][c8] = *(const bf8_t*)&B[(size_t)(bn + r) * 768 + k0 + c8];
        }
        __syncthreads();
#pragma unroll
        for (int kk = 0; kk < 2; kk++) {
            bf8_t a[2], bb[2];
#pragma unroll
            for (int mt = 0; mt < 2; mt++)
                a[mt] = *(const bf8_t*)&Al[wm + mt * 16 + fr][kk * 32 + fg * 8];
#pragma unroll
            for (int nt = 0; nt < 2; nt++)
                bb[nt] = *(const bf8_t*)&Bl[wn + nt * 16 + fr][kk * 32 + fg * 8];
#pragma unroll
            for (int mt = 0; mt < 2; mt++)
#pragma unroll
                for (int nt = 0; nt < 2; nt++)
                    acc[mt][nt] = __builtin_amdgcn_mfma_f32_16x16x32_bf16(
                        a[mt], bb[nt], acc[mt][nt], 0, 0, 0);
        }
        __syncthreads();
    }
    // C/D: col = lane&15, row = (lane>>4)*4 + reg   [m89/m91]
#pragma unroll
    for (int nt = 0; nt < 2; nt++) {
        int ng = bn + wn + nt * 16 + fr;
        float bvv = bias[ng];
        if (job == 0) {
            int hh = ng & 63;
#pragma unroll
            for (int mt = 0; mt < 2; mt++) {
#pragma unroll
                for (int r = 0; r < 4; r++) {
                    int rg = bm + wm + mt * 16 + fg * 4 + r;
                    int bb2 = rg >> 10, t = rg & 1023;
                    KSb[(((size_t)bb2 * 12 + z) * 1024 + t) * 64 + hh] =
                        f2bf(ftanh(acc[mt][nt][r] + bvv));
                }
            }
        } else {
            unsigned short* outp = (job == 1) ? QSbf : WQLbf;
#pragma unroll
            for (int mt = 0; mt < 2; mt++) {
#pragma unroll
                for (int r = 0; r < 4; r++) {
                    int rg = bm + wm + mt * 16 + fg * 4 + r;
                    if (rg < Mw)
                        outp[(size_t)rg * 768 + ng] = f2bf(acc[mt][nt][r] + bvv);
                }
            }
        }
    }
}

// ---- attn7: 64-row t-chunks; kwl (MFMA) + scores (MFMA) + exp-sums --------
// block = (b, z, ts of 64 t); 768 blocks; 4 waves. tanh(H) from f32 inline.
__global__ __launch_bounds__(256) void attn7_kernel(
    const unsigned short* __restrict__ KSb, const unsigned short* __restrict__ QSbf,
    const float* __restrict__ H, const unsigned short* __restrict__ WQLbf,
    float* __restrict__ pd, float* __restrict__ pn)
{
    __shared__ unsigned short KTl[64][72];   // phase1: tanh(H); phase3: K tile
    __shared__ unsigned short Wl[64][72];
    __shared__ float kwl[64][50];
    const int blk = blockIdx.x;
    const int ts = blk & 15;
    const int z  = (blk >> 4) % 12;
    const int b  = blk / 192;
    const int tid = threadIdx.x;
    const int lane = tid & 63, w = tid >> 6;
    const int fr = lane & 15, fg = lane >> 4;

    // phase 0: stage tanh(H z-slice) rows ts*64..+64 (f32 load) + WQL slice
    const float* hb = H + (size_t)(b * 1024 + ts * 64) * 768 + z * 64;
#pragma unroll
    for (int i = 0; i < 2; i++) {
        int f = tid + i * 256;
        int r = f >> 3, c8 = (f & 7) << 3;
        float4 v0 = *(const float4*)&hb[(size_t)r * 768 + c8];
        float4 v1 = *(const float4*)&hb[(size_t)r * 768 + c8 + 4];
        unsigned short t8[8] = {f2bf(ftanh(v0.x)), f2bf(ftanh(v0.y)),
                                f2bf(ftanh(v0.z)), f2bf(ftanh(v0.w)),
                                f2bf(ftanh(v1.x)), f2bf(ftanh(v1.y)),
                                f2bf(ftanh(v1.z)), f2bf(ftanh(v1.w))};
        *(bf8_t*)&KTl[r][c8] = *(const bf8_t*)t8;
    }
#pragma unroll
    for (int i = 0; i < 2; i++) {
        int f = tid + i * 256;
        int r = f >> 3, c8 = (f & 7) << 3;
        *(bf8_t*)&Wl[r][c8] = *(const bf8_t*)&WQLbf[(size_t)r * 768 + z * 64 + c8];
    }
    __syncthreads();

    // phase 1: kwl = tanh(H) @ WQL^T (wave w: rows w*16..+16; N=64, K=64)
    {
        const int wm2 = w * 16;
        f32x4 a1[4] = {};
#pragma unroll
        for (int kk = 0; kk < 2; kk++) {
            bf8_t a = *(const bf8_t*)&KTl[wm2 + fr][kk * 32 + fg * 8];
#pragma unroll
            for (int nt = 0; nt < 4; nt++) {
                bf8_t bb = *(const bf8_t*)&Wl[nt * 16 + fr][kk * 32 + fg * 8];
                a1[nt] = __builtin_amdgcn_mfma_f32_16x16x32_bf16(a, bb, a1[nt], 0, 0, 0);
            }
        }
#pragma unroll
        for (int nt = 0; nt < 4; nt++) {
            int c = nt * 16 + fr;
            if (c < 50) {
#pragma unroll
                for (int r = 0; r < 4; r++)
                    kwl[wm2 + fg * 4 + r][c] = a1[nt][r];
            }
        }
    }
    __syncthreads();

    // phase 2: stage K tile over the tanh(H) tile
    const unsigned short* ksb = KSb + ((size_t)((b * 12 + z) * 1024) + ts * 64) * 64;
#pragma unroll
    for (int i = 0; i < 2; i++) {
        int f = tid + i * 256;
        int r = f >> 3, c8 = (f & 7) << 3;
        *(bf8_t*)&KTl[r][c8] = *(const bf8_t*)&ksb[(size_t)r * 64 + c8];
    }
    __syncthreads();

    // phase 3: scores + exp-sums. wave w owns cs-tiles nt = w, w+4, w+8[, 12].
    bf8_t af[8];
#pragma unroll
    for (int mt = 0; mt < 4; mt++)
#pragma unroll
        for (int kk = 0; kk < 2; kk++)
            af[mt * 2 + kk] = *(const bf8_t*)&KTl[mt * 16 + fr][kk * 32 + fg * 8];

    for (int nt = w; nt < 13; nt += 4) {
        const int cs = nt * 16 + fr;
        const bool live = (cs < 200);
        const int kc = live ? (cs >> 2) : 0;
        bf8_t b0 = *(const bf8_t*)&QSbf[(size_t)(nt * 16 + fr) * 768 + z * 64 + fg * 8];
        bf8_t b1 = *(const bf8_t*)&QSbf[(size_t)(nt * 16 + fr) * 768 + z * 64 + 32 + fg * 8];

        float den = 0.f, num = 0.f;
#pragma unroll
        for (int mt = 0; mt < 4; mt++) {
            f32x4 sc = {};
            sc = __builtin_amdgcn_mfma_f32_16x16x32_bf16(af[mt * 2 + 0], b0, sc, 0, 0, 0);
            sc = __builtin_amdgcn_mfma_f32_16x16x32_bf16(af[mt * 2 + 1], b1, sc, 0, 0, 0);
#pragma unroll
            for (int j = 0; j < 4; j++) {
                float p = __expf(sc[j]);               // |score| <~ 15: f32-safe
                den += p;
                num += p * kwl[mt * 16 + fg * 4 + j][kc];
            }
        }
        den += __shfl_xor(den, 16); num += __shfl_xor(num, 16);
        den += __shfl_xor(den, 32); num += __shfl_xor(num, 32);
        if (fg == 0 && live) {
            size_t R = ((size_t)b * 200 + cs) * 12 + z;
            pd[R * 16 + ts] = den;
            pn[R * 16 + ts] = num;
        }
    }
}

// ---- reduce: block per (b,c); lane j<48 owns (z,s); 16 t-partials ---------
__global__ __launch_bounds__(64) void reduce_kernel(
    const float* __restrict__ pd, const float* __restrict__ pn,
    float* __restrict__ out)
{
    const int bc = blockIdx.x;           // b*50 + c
    const int b = bc / 50, c = bc % 50;
    const int j = threadIdx.x;
    float ratio = 0.f;
    if (j < 48) {
        int zz = j >> 2, s = j & 3;
        size_t R = ((size_t)b * 200 + (c * 4 + s)) * 12 + zz;
        float D = 0.f, N = 0.f;
#pragma unroll
        for (int t = 0; t < 16; t++) {
            D += pd[R * 16 + t];
            N += pn[R * 16 + t];
        }
        ratio = N / D;
    }
#pragma unroll
    for (int off = 32; off; off >>= 1) ratio += __shfl_xor(ratio, off);
    if (j == 0) out[bc] = 0.25f * ratio;
}

extern "C" void kernel_launch(void* const* d_in, const int* in_sizes, int n_in,
                              void* d_out, int out_size, void* d_ws, size_t ws_size,
                              hipStream_t stream) {
    const float* Q    = (const float*)d_in[0];
    const float* H    = (const float*)d_in[1];
    const float* ql   = (const float*)d_in[2];
    const float* WQ_w = (const float*)d_in[3];
    const float* WQ_b = (const float*)d_in[4];
    const float* WK_w = (const float*)d_in[5];
    const float* WK_b = (const float*)d_in[6];
    const float* WV_w = (const float*)d_in[7];
    const float* WV_b = (const float*)d_in[8];
    float* out = (float*)d_out;

    // ws layout in f32 SLOTS (bf16 buffers use elem_count/2 slots):
    //  WT: 768*768 bf16 = 294,912 f32 ; KSb: 4096*768 bf16 = 1,572,864 f32
    //  QSbf: 208*768/2 = 79,872 ; WQLbf: 24,576 ; pd/pn: 9600*16 = 153,600 ea
    float* ws = (float*)d_ws;
    unsigned short* WTk   = (unsigned short*)ws;               // [0, 294912)
    unsigned short* WTq   = (unsigned short*)(ws + 294912);    // [294912, 589824)
    unsigned short* WTv   = (unsigned short*)(ws + 589824);    // [589824, 884736)
    unsigned short* KSb   = (unsigned short*)(ws + 884736);    // [884736, 2457600)
    unsigned short* QSbf  = (unsigned short*)(ws + 2457600);   // [2457600, 2537472)
    unsigned short* WQLbf = (unsigned short*)(ws + 2537472);   // [2537472, 2562048)
    float* pd             = ws + 2562048;                      // [2562048, 2715648)
    float* pn             = ws + 2715648;                      // [2715648, 2869248)
    (void)in_sizes; (void)n_in; (void)out_size; (void)ws_size;

    prep_kernel<<<432, 256, 0, stream>>>(WK_w, WQ_w, WV_w, WTk, WTq, WTv);
    gemm_all_kernel<<<828, 256, 0, stream>>>(H, Q, ql, WTk, WTq, WTv,
                                             WK_b, WQ_b, WV_b, KSb, QSbf, WQLbf);
    attn7_kernel<<<768, 256, 0, stream>>>(KSb, QSbf, H, WQLbf, pd, pn);
    reduce_kernel<<<200, 64, 0, stream>>>(pd, pn, out);
}